// Round 13
// baseline (125.270 us; speedup 1.0000x reference)
//
#include <hip/hip_runtime.h>

typedef unsigned short u16;
typedef __attribute__((ext_vector_type(4))) unsigned short u16x4;
typedef __attribute__((ext_vector_type(8))) unsigned short u16x8;
typedef __attribute__((ext_vector_type(8))) short bf16x8;
typedef __attribute__((ext_vector_type(4))) float f32x4;

constexpr int Bn = 8, Tn = 2048, Dn = 512, DKn = 128;
constexpr int QB = 64;      // query rows per pv tile
constexpr int WJ = 832;     // padded union window for pv = 13*64
constexpr int NCH = 13;     // pv K-chunks of 64
constexpr int WQB = 16;     // query rows per weights block
constexpr int WST = 776;    // weights S LDS stride (u16)

__device__ inline u16 f2bf(float f) {
  unsigned u = __float_as_uint(f);
  return (u16)((u + 0x7FFFu + ((u >> 16) & 1u)) >> 16);
}
__device__ inline float bf2f(u16 h) {
  return __uint_as_float(((unsigned)h) << 16);
}
__device__ inline void gload16(const void* g, void* l) {
  __builtin_amdgcn_global_load_lds(
      (const __attribute__((address_space(1))) unsigned int*)g,
      (__attribute__((address_space(3))) unsigned int*)l, 16, 0, 0);
}
__device__ inline f32x4 mfma16(bf16x8 a, bf16x8 b, f32x4 c) {
  return __builtin_amdgcn_mfma_f32_16x16x32_bf16(a, b, c, 0, 0, 0);
}

// ---------------------------------------------------------------------------
// Kernel 1: xT[b][d][t] = bf16(x[b][t][d]) AND xbf[b][t][d] = bf16(x[b][t][d]).
// ---------------------------------------------------------------------------
__global__ __launch_bounds__(256) void xpose_kernel(
    const float* __restrict__ x, u16* __restrict__ xT, u16* __restrict__ xbf) {
  __shared__ u16 tile[64][72];
  const int blk = blockIdx.x;
  const int b = blk >> 8;                 // 256 tiles per batch
  const int rem = blk & 255;
  const int t0 = (rem >> 3) * 64, d0 = (rem & 7) * 64;
  const int tid = threadIdx.x;

#pragma unroll
  for (int it = 0; it < 4; ++it) {
    int r = (tid >> 4) + it * 16;
    int c = (tid & 15) * 4;
    float4 v = *(const float4*)&x[(size_t)(b * Tn + t0 + r) * Dn + d0 + c];
    u16 b0 = f2bf(v.x), b1 = f2bf(v.y), b2 = f2bf(v.z), b3 = f2bf(v.w);
    tile[c + 0][r] = b0;
    tile[c + 1][r] = b1;
    tile[c + 2][r] = b2;
    tile[c + 3][r] = b3;
    u16x4 pv; pv[0] = b0; pv[1] = b1; pv[2] = b2; pv[3] = b3;
    *(u16x4*)&xbf[(size_t)(b * Tn + t0 + r) * Dn + d0 + c] = pv;
  }
  __syncthreads();
  const int dr = tid >> 2, ts = (tid & 3) * 16;
  u16x8 v0 = *(const u16x8*)&tile[dr][ts];
  u16x8 v1 = *(const u16x8*)&tile[dr][ts + 8];
  u16* dst = xT + (size_t)(b * Dn + d0 + dr) * Tn + t0 + ts;
  *(u16x8*)dst = v0;
  *(u16x8*)(dst + 8) = v1;
}

// ---------------------------------------------------------------------------
// Kernel 2: weight prep.  Both Wq|Wk and Wo go to FRAGMENT-LINEAR layouts:
// value WT[n][d] stored at
//   (((n>>4)*16 + (d>>5))*64 + ((((d>>3)&3)<<4) | (n&15)))*8 + (d&7)
// so one MFMA A-fragment (16 n-rows x 32 d) = 1 KB contiguous, lane-linear.
// WqkTf: n in 0..255 (q cols | k cols), d in 0..511.  WoTf: n,d in 0..511.
// ---------------------------------------------------------------------------
__global__ __launch_bounds__(256) void wprep_kernel(
    const float* __restrict__ Wq, const float* __restrict__ Wk,
    const float* __restrict__ Wo,
    u16* __restrict__ WqkTf, u16* __restrict__ WoTf) {
  __shared__ u16 tile[64][72];
  const int tid = threadIdx.x;
  const int blk = blockIdx.x;
  const float* src;
  int srcC, r0, c0, rowOff;
  if (blk < 32) {
    src = (blk < 16) ? Wq : Wk;
    rowOff = (blk < 16) ? 0 : 128;
    int t = blk & 15;
    r0 = (t >> 1) * 64; c0 = (t & 1) * 64;
    srcC = 128;
  } else {
    int t = blk - 32;
    src = Wo; rowOff = 0;
    r0 = (t >> 3) * 64; c0 = (t & 7) * 64;
    srcC = 512;
  }
#pragma unroll
  for (int it = 0; it < 4; ++it) {
    int r = (tid >> 4) + it * 16;
    int c = (tid & 15) * 4;
    float4 v = *(const float4*)&src[(size_t)(r0 + r) * srcC + c0 + c];
    tile[c + 0][r] = f2bf(v.x);
    tile[c + 1][r] = f2bf(v.y);
    tile[c + 2][r] = f2bf(v.z);
    tile[c + 3][r] = f2bf(v.w);
  }
  __syncthreads();
  const int dr = tid >> 2, ts = (tid & 3) * 16;
  u16x8 v0 = *(const u16x8*)&tile[dr][ts];
  u16x8 v1 = *(const u16x8*)&tile[dr][ts + 8];
  int n = rowOff + c0 + dr;
  int d0 = r0 + ts, d1 = d0 + 8;
  size_t a0 = (size_t)(((n >> 4) * 16 + (d0 >> 5)) * 64 +
                       ((((d0 >> 3) & 3) << 4) | (n & 15))) * 8;
  size_t a1 = (size_t)(((n >> 4) * 16 + (d1 >> 5)) * 64 +
                       ((((d1 >> 3) & 3) << 4) | (n & 15))) * 8;
  u16* dst = (blk < 32) ? WqkTf : WoTf;
  *(u16x8*)&dst[a0] = v0;
  *(u16x8*)&dst[a1] = v1;
}

// ---------------------------------------------------------------------------
// Kernel 3: q|k = xbf @ Wqk + bias, BARRIER-FREE (no LDS).
// Block = 32 rows x 256 cols, 256 threads (4 waves x 64-col quarters).
// A-frags from fragment-linear WqkTf (1 KB coalesced, L2-resident 256 KB);
// B-frags per-lane direct from xbf rows (16 KB/block, L1-resident, 4x reuse).
// Operand-swapped layout (verified in out_ln R11/R12): lane l, reg i:
//   outcol = w*64 + m*16 + (l>>4)*4 + i ; trow = nh*16 + (l&15)
// ---------------------------------------------------------------------------
__global__ __launch_bounds__(256, 4) void qk_mfma_kernel(
    const u16* __restrict__ xbf, const u16* __restrict__ WqkTf,
    const float* __restrict__ bq, const float* __restrict__ bk,
    u16* __restrict__ qbf, u16* __restrict__ kbf) {
  const int tid = threadIdx.x, w = tid >> 6, l = tid & 63;
  const int r0 = blockIdx.x * 32;      // global row (b*Tn + t), linear

  f32x4 acc[4][2];
#pragma unroll
  for (int m = 0; m < 4; ++m)
#pragma unroll
    for (int nh = 0; nh < 2; ++nh) acc[m][nh] = (f32x4){0.f,0.f,0.f,0.f};

  const u16* aptr = WqkTf + (size_t)(w * 4) * 16 * 512 + l * 8;   // + (m*16+c)*512
  const u16* bptr = xbf + (size_t)(r0 + (l & 15)) * Dn + (l >> 4) * 8;  // + nh*16*Dn + c*32

#pragma unroll 4
  for (int c = 0; c < 16; ++c) {
    bf16x8 bfr[2];
#pragma unroll
    for (int nh = 0; nh < 2; ++nh)
      bfr[nh] = *(const bf16x8*)(bptr + (size_t)nh * 16 * Dn + c * 32);
#pragma unroll
    for (int m = 0; m < 4; ++m) {
      bf16x8 afr = *(const bf16x8*)(aptr + (size_t)(m * 16 + c) * 512);
      acc[m][0] = mfma16(afr, bfr[0], acc[m][0]);
      acc[m][1] = mfma16(afr, bfr[1], acc[m][1]);
    }
  }

  // epilogue: bias + bf16 pack, u16x4 stores.  Waves 0-1 -> q, 2-3 -> k.
  u16* outp = (w < 2) ? qbf : kbf;
  const float* bias = (w < 2) ? bq : bk;
#pragma unroll
  for (int m = 0; m < 4; ++m) {
    int outc = w * 64 + m * 16 + (l >> 4) * 4;   // 0..255
    int lc = outc & 127;
    float4 b4 = *(const float4*)&bias[lc];
#pragma unroll
    for (int nh = 0; nh < 2; ++nh) {
      int row = r0 + nh * 16 + (l & 15);
      u16x4 o;
      o[0] = f2bf(acc[m][nh][0] + b4.x);
      o[1] = f2bf(acc[m][nh][1] + b4.y);
      o[2] = f2bf(acc[m][nh][2] + b4.z);
      o[3] = f2bf(acc[m][nh][3] + b4.w);
      *(u16x4*)&outp[(size_t)row * DKn + lc] = o;
    }
  }
}

// ---------------------------------------------------------------------------
// Kernel 4: banded scores + 3-window softmax -> combined weights.
// Block = 16 query rows, 256 threads.  XCD swizzle: one batch per XCD.
// ---------------------------------------------------------------------------
__global__ __launch_bounds__(256) void weights_kernel(
    const u16* __restrict__ qbf, const u16* __restrict__ kbf,
    u16* __restrict__ Wg) {
  __shared__ u16 S[WQB * WST];          // 24.8 KB bf16 e-values
  __shared__ float spart[4][WQB][3];    // 768 B ring-sum partials
  const int tid = threadIdx.x, w = tid >> 6, l = tid & 63;
  // XCD swizzle: 1024 blocks = 8 XCD x 128; XCD x owns batch x entirely.
  const int blk = (blockIdx.x & 7) * 128 + (blockIdx.x >> 3);
  const int b = blk >> 7;
  const int tt = blk & 127;
  const int t0 = tt * WQB;
  const int jbase = t0 - 360;
  const float scale = 0.08838834764831845f;   // 1/sqrt(128)

  // q fragments in registers (same 16 rows for all 4 waves)
  bf16x8 a[4];
  {
    int row = t0 + (l & 15);
    const u16* qp = qbf + (size_t)(b * Tn + row) * DKn + (l >> 4) * 8;
#pragma unroll
    for (int kk = 0; kk < 4; ++kk) a[kk] = *(const bf16x8*)(qp + kk * 32);
  }

  float s0[4], s1[4], s2[4];
#pragma unroll
  for (int i = 0; i < 4; ++i) { s0[i] = 0.f; s1[i] = 0.f; s2[i] = 0.f; }
  const int rbase = 4 * (l >> 4);

  // MFMA loop: 12 chunks of 64 j (wave w owns j-quarter w), no barriers
  for (int c = 0; c < 12; ++c) {
    int jj = c * 64 + w * 16 + (l & 15);
    int j = jbase + jj;
    int jc = j < 0 ? 0 : (j > Tn - 1 ? Tn - 1 : j);
    const u16* kp = kbf + (size_t)(b * Tn + jc) * DKn + (l >> 4) * 8;
    f32x4 acc = {0.f, 0.f, 0.f, 0.f};
#pragma unroll
    for (int kk = 0; kk < 4; ++kk)
      acc = mfma16(a[kk], *(const bf16x8*)(kp + kk * 32), acc);
    bool valid = (j >= 0) && (j < Tn);
#pragma unroll
    for (int i = 0; i < 4; ++i) {
      int r = rbase + i;
      int dist = jj - r - 360; dist = dist < 0 ? -dist : dist;
      float e = __expf(acc[i] * scale);
      e = (valid && dist <= 360) ? e : 0.f;
      S[r * WST + jj] = f2bf(e);
      bool in0 = dist <= 12, in1 = dist <= 84;
      s0[i] += in0 ? e : 0.f;
      s1[i] += (in1 && !in0) ? e : 0.f;
      s2[i] += in1 ? 0.f : e;
    }
  }

  // reduce ring sums over the 16 col-lanes, store per-wave partials
#pragma unroll
  for (int o = 1; o < 16; o <<= 1)
#pragma unroll
    for (int i = 0; i < 4; ++i) {
      s0[i] += __shfl_xor(s0[i], o);
      s1[i] += __shfl_xor(s1[i], o);
      s2[i] += __shfl_xor(s2[i], o);
    }
  if ((l & 15) == 0) {
#pragma unroll
    for (int i = 0; i < 4; ++i) {
      spart[w][rbase + i][0] = s0[i];
      spart[w][rbase + i][1] = s1[i];
      spart[w][rbase + i][2] = s2[i];
    }
  }
  __syncthreads();

  // combine & write.  Wave w owns rows 4w..4w+3.
  const int off = (tt & 3) * 16;            // row/col offset within pv tile
  const int pvblk = b * 32 + (tt >> 2);
#pragma unroll
  for (int rr = 0; rr < 4; ++rr) {
    int r = 4 * w + rr;
    float L0 = spart[0][r][0] + spart[1][r][0] + spart[2][r][0] + spart[3][r][0];
    float L1 = L0 + spart[0][r][1] + spart[1][r][1] + spart[2][r][1] + spart[3][r][1];
    float L2 = L1 + spart[0][r][2] + spart[1][r][2] + spart[2][r][2] + spart[3][r][2];
    float F2 = (1.f / 3.f) / L2;
    float F1 = (1.f / 3.f) / L1 + F2;
    float F0 = (1.f / 3.f) / L0 + F1;
    const int center = r + 360;
    u16* wrow = Wg + ((size_t)pvblk * QB + off + r) * WJ;
#pragma unroll
    for (int t = 0; t < 6; ++t) {
      int jjw = 2 * l + 128 * t;
      if (jjw < 736) {
        unsigned pv2 = *(const unsigned*)&S[r * WST + jjw];
        float e0 = bf2f((u16)(pv2 & 0xffff));
        float e1 = bf2f((u16)(pv2 >> 16));
        int d0 = jjw - center; d0 = d0 < 0 ? -d0 : d0;
        int d1 = jjw + 1 - center; d1 = d1 < 0 ? -d1 : d1;
        float c0 = e0 * (d0 <= 12 ? F0 : (d0 <= 84 ? F1 : F2));
        float c1 = e1 * (d1 <= 12 ? F0 : (d1 <= 84 ? F1 : F2));
        unsigned o2 = (unsigned)f2bf(c0) | ((unsigned)f2bf(c1) << 16);
        *(unsigned*)&wrow[off + jjw] = o2;
      }
    }
    // pad: zero pv columns [0,off) and [off+736, 832)
    if (l < 48) {
      int jjp = (l < (off >> 1)) ? 2 * l : 736 + 2 * l;
      *(unsigned*)&wrow[jjp] = 0u;
    }
  }
}

// ---------------------------------------------------------------------------
// Kernel 5: PV GEMM, split-D.  Block = 64 t x 256 d (half of D), KC=64.
// OUT[64 x 256] = Wg[64 x 832] @ xwin[832 x 256].  80 KB LDS -> 2 blocks/CU.
// XCD swizzle: 512 blocks = 8 XCD x 64; XCD x owns batch x (xT 2 MB L2-fit).
// ---------------------------------------------------------------------------
__global__ __launch_bounds__(512) void pv_kernel(
    const u16* __restrict__ Wg, const u16* __restrict__ xT,
    u16* __restrict__ accbf) {
  __shared__ u16 xs[2][256 * 64];  // 2 x 32 KB
  __shared__ u16 ws[2][QB * 64];   // 2 x 8 KB
  const int tid = threadIdx.x;
  const int w = tid >> 6, l = tid & 63;
  const int work = (blockIdx.x & 7) * 64 + (blockIdx.x >> 3);
  const int b = work >> 6;
  const int rem = work & 63;
  const int tt = rem >> 1;
  const int dh = rem & 1;          // which 256-col half of D
  const int t064 = tt * QB;
  const int jbase = t064 - 360;
  const int pvblk = b * 32 + tt;
  const int wr = w >> 2, wc = w & 3;   // wave tile: 32 t x 64 d

  f32x4 acc[2][4];
#pragma unroll
  for (int mm = 0; mm < 2; ++mm)
#pragma unroll
    for (int n = 0; n < 4; ++n) acc[mm][n] = (f32x4){0.f,0.f,0.f,0.f};

  auto stage = [&](int c, int buf) {
#pragma unroll
    for (int ii = 0; ii < 4; ++ii) {
      int i = 4 * w + ii;
      int d = i * 8 + (l >> 3);          // 0..255 local d row
      int ss = (l & 7) ^ (d & 7);
      int g = jbase + c * 64 + ss * 8;
      g = g < 0 ? 0 : (g > Tn - 8 ? Tn - 8 : g);
      gload16(xT + ((size_t)(b * Dn + dh * 256 + d) * Tn + g),
              (char*)&xs[buf][0] + i * 1024);
    }
    int row = 8 * w + (l >> 3);
    int ss = (l & 7) ^ (row & 7);
    gload16(Wg + ((size_t)(pvblk * QB + row)) * WJ + c * 64 + ss * 8,
            (char*)&ws[buf][0] + w * 1024);
  };

  stage(0, 0);
  __syncthreads();
  for (int c = 0; c < NCH; ++c) {
    if (c + 1 < NCH) stage(c + 1, (c + 1) & 1);
    const u16* xb = &xs[c & 1][0];
    const u16* wb = &ws[c & 1][0];
#pragma unroll
    for (int kk = 0; kk < 2; ++kk) {
      int rA0 = wr * 32 + (l & 15);
      int sA = ((l >> 4) + 4 * kk) ^ (rA0 & 7);
      bf16x8 a0 = *(const bf16x8*)(wb + rA0 * 64 + sA * 8);
      bf16x8 a1 = *(const bf16x8*)(wb + (rA0 + 16) * 64 + sA * 8);
#pragma unroll
      for (int n = 0; n < 4; ++n) {
        int rB = wc * 64 + n * 16 + (l & 15);
        int sB = ((l >> 4) + 4 * kk) ^ (rB & 7);
        bf16x8 bv = *(const bf16x8*)(xb + rB * 64 + sB * 8);
        acc[0][n] = mfma16(a0, bv, acc[0][n]);
        acc[1][n] = mfma16(a1, bv, acc[1][n]);
      }
    }
    __syncthreads();
  }
#pragma unroll
  for (int mm = 0; mm < 2; ++mm)
#pragma unroll
    for (int n = 0; n < 4; ++n)
#pragma unroll
      for (int i = 0; i < 4; ++i) {
        int row = wr * 32 + mm * 16 + 4 * (l >> 4) + i;
        int col = dh * 256 + wc * 64 + n * 16 + (l & 15);
        accbf[(size_t)(b * Tn + t064 + row) * Dn + col] = f2bf(acc[mm][n][i]);
      }
}

// ---------------------------------------------------------------------------
// Kernel 6: OUT = LN(accbf @ Wo + bo + x) * gamma + beta, MFMA fused.
// BARRIER-FREE K-loop (weights_kernel pattern): no LDS staging.
// A-frags from fragment-linear WoTf (coalesced 1 KB loads); B-frags direct
// from accbf (32 KB tile, L1-resident, 8x reuse).  Operand-swapped (OUT^T
// tiles) so each f32x4 holds 4 consecutive out-cols -> float4 epilogue.
// ---------------------------------------------------------------------------
__global__ __launch_bounds__(512, 4) void out_ln_mfma_kernel(
    const u16* __restrict__ accbf, const float* __restrict__ x,
    const u16* __restrict__ WoTf, const float* __restrict__ bo,
    const float* __restrict__ gamma, const float* __restrict__ beta,
    float* __restrict__ out) {
  __shared__ float red[32][8][2];     // 2 KB
  const int tid = threadIdx.x, w = tid >> 6, l = tid & 63;
  const int r0 = blockIdx.x * 32;

  // wave w owns out-cols [w*64, w*64+64).  Lane l, reg i:
  //   outcol = w*64 + m*16 + (l>>4)*4 + i ; trow = nh*16 + (l&15)
  f32x4 acc[4][2];
#pragma unroll
  for (int m = 0; m < 4; ++m)
#pragma unroll
    for (int nh = 0; nh < 2; ++nh) acc[m][nh] = (f32x4){0.f,0.f,0.f,0.f};

  // per-lane base pointers
  const u16* aptr = WoTf + (size_t)(w * 4) * 16 * 512 + l * 8;   // + (m*16+c)*512
  const u16* bptr = accbf + (size_t)(r0 + (l & 15)) * Dn + (l >> 4) * 8;  // + nh*16*Dn + c*32

#pragma unroll 4
  for (int c = 0; c < 16; ++c) {
    bf16x8 bfr[2];
#pragma unroll
    for (int nh = 0; nh < 2; ++nh)
      bfr[nh] = *(const bf16x8*)(bptr + (size_t)nh * 16 * Dn + c * 32);
#pragma unroll
    for (int m = 0; m < 4; ++m) {
      bf16x8 afr = *(const bf16x8*)(aptr + (size_t)(m * 16 + c) * 512);
      acc[m][0] = mfma16(afr, bfr[0], acc[m][0]);
      acc[m][1] = mfma16(afr, bfr[1], acc[m][1]);
    }
  }

  // ---- epilogue: all register-resident, float4 I/O ----
  float s[2] = {0.f, 0.f}, s2[2] = {0.f, 0.f};
#pragma unroll
  for (int nh = 0; nh < 2; ++nh) {
    int trow_g = r0 + nh * 16 + (l & 15);
#pragma unroll
    for (int m = 0; m < 4; ++m) {
      int outc = w * 64 + m * 16 + (l >> 4) * 4;
      float4 xq  = *(const float4*)&x[(size_t)trow_g * Dn + outc];
      float4 bo4 = *(const float4*)&bo[outc];
      acc[m][nh][0] += bo4.x + xq.x;
      acc[m][nh][1] += bo4.y + xq.y;
      acc[m][nh][2] += bo4.z + xq.z;
      acc[m][nh][3] += bo4.w + xq.w;
#pragma unroll
      for (int i = 0; i < 4; ++i) {
        float v = acc[m][nh][i];
        s[nh] += v; s2[nh] += v * v;
      }
    }
  }
  // reduce over the 4 lanes sharing (l&15): bits 4,5 of lane id
#pragma unroll
  for (int nh = 0; nh < 2; ++nh) {
    s[nh]  += __shfl_xor(s[nh], 16);  s[nh]  += __shfl_xor(s[nh], 32);
    s2[nh] += __shfl_xor(s2[nh], 16); s2[nh] += __shfl_xor(s2[nh], 32);
  }
  if (l < 16) {
#pragma unroll
    for (int nh = 0; nh < 2; ++nh) {
      red[nh * 16 + l][w][0] = s[nh];
      red[nh * 16 + l][w][1] = s2[nh];
    }
  }
  __syncthreads();
#pragma unroll
  for (int nh = 0; nh < 2; ++nh) {
    int trow = nh * 16 + (l & 15);
    float ts = 0.f, ts2 = 0.f;
#pragma unroll
    for (int ww = 0; ww < 8; ++ww) {
      ts  += red[trow][ww][0];
      ts2 += red[trow][ww][1];
    }
    float mean = ts * (1.f / 512.f);
    float var  = ts2 * (1.f / 512.f) - mean * mean;
    float inv  = rsqrtf(var + 1e-5f);
    size_t grow = (size_t)(r0 + trow) * Dn;
#pragma unroll
    for (int m = 0; m < 4; ++m) {
      int outc = w * 64 + m * 16 + (l >> 4) * 4;
      float4 g4  = *(const float4*)&gamma[outc];
      float4 be4 = *(const float4*)&beta[outc];
      float4 o4;
      o4.x = (acc[m][nh][0] - mean) * inv * g4.x + be4.x;
      o4.y = (acc[m][nh][1] - mean) * inv * g4.y + be4.y;
      o4.z = (acc[m][nh][2] - mean) * inv * g4.z + be4.z;
      o4.w = (acc[m][nh][3] - mean) * inv * g4.w + be4.w;
      *(float4*)&out[grow + outc] = o4;
    }
  }
}

// ---------------------------------------------------------------------------
extern "C" void kernel_launch(void* const* d_in, const int* in_sizes, int n_in,
                              void* d_out, int out_size, void* d_ws, size_t ws_size,
                              hipStream_t stream) {
  const float* x     = (const float*)d_in[0];
  const float* Wq    = (const float*)d_in[1];
  const float* bq    = (const float*)d_in[2];
  const float* Wk    = (const float*)d_in[3];
  const float* bk    = (const float*)d_in[4];
  const float* Wo    = (const float*)d_in[5];
  const float* bo    = (const float*)d_in[6];
  const float* gamma = (const float*)d_in[7];
  const float* beta  = (const float*)d_in[8];
  float* out = (float*)d_out;

  // workspace (u16 elems)
  u16* qbf   = (u16*)d_ws;
  u16* kbf   = qbf   + (size_t)Bn * Tn * DKn;          // +2,097,152
  u16* xT    = kbf   + (size_t)Bn * Tn * DKn;          // +2,097,152
  u16* xbf   = xT    + (size_t)Bn * Dn * Tn;           // +8,388,608
  u16* Wg    = xbf   + (size_t)Bn * Tn * Dn;           // +8,388,608
  u16* accbf = Wg    + (size_t)Bn * 32 * QB * WJ;      // +13,631,488
  u16* WqkTf = accbf + (size_t)Bn * Tn * Dn;           // +8,388,608
  u16* WoTf  = WqkTf + (size_t)256 * 512;              // +131,072

  xpose_kernel<<<Bn * 256, 256, 0, stream>>>(x, xT, xbf);
  wprep_kernel<<<96, 256, 0, stream>>>(Wq, Wk, Wo, WqkTf, WoTf);
  qk_mfma_kernel<<<Bn * Tn / 32, 256, 0, stream>>>(xbf, WqkTf, bq, bk, qbf, kbf);
  weights_kernel<<<Bn * 128, 256, 0, stream>>>(qbf, kbf, Wg);
  pv_kernel<<<Bn * 64, 512, 0, stream>>>(Wg, xT, accbf);
  out_ln_mfma_kernel<<<Bn * Tn / 32, 512, 0, stream>>>(accbf, x, WoTf, bo, gamma, beta, out);
}

// Round 14
// 110.388 us; speedup vs baseline: 1.1348x; 1.1348x over previous
//
#include <hip/hip_runtime.h>

typedef unsigned short u16;
typedef __attribute__((ext_vector_type(4))) unsigned short u16x4;
typedef __attribute__((ext_vector_type(8))) unsigned short u16x8;
typedef __attribute__((ext_vector_type(8))) short bf16x8;
typedef __attribute__((ext_vector_type(4))) float f32x4;

constexpr int Bn = 8, Tn = 2048, Dn = 512, DKn = 128;
constexpr int QB = 64;      // query rows per pv tile
constexpr int WJ = 832;     // padded union window for pv = 13*64
constexpr int NCH = 13;     // pv K-chunks of 64
constexpr int WQB = 16;     // query rows per weights block
constexpr int WST = 776;    // weights S LDS stride (u16)

__device__ inline u16 f2bf(float f) {
  unsigned u = __float_as_uint(f);
  return (u16)((u + 0x7FFFu + ((u >> 16) & 1u)) >> 16);
}
__device__ inline float bf2f(u16 h) {
  return __uint_as_float(((unsigned)h) << 16);
}
__device__ inline void gload16(const void* g, void* l) {
  __builtin_amdgcn_global_load_lds(
      (const __attribute__((address_space(1))) unsigned int*)g,
      (__attribute__((address_space(3))) unsigned int*)l, 16, 0, 0);
}
__device__ inline f32x4 mfma16(bf16x8 a, bf16x8 b, f32x4 c) {
  return __builtin_amdgcn_mfma_f32_16x16x32_bf16(a, b, c, 0, 0, 0);
}

// ---------------------------------------------------------------------------
// Kernel 1: xT[b][d][t] = bf16(x[b][t][d]) AND xbf[b][t][d] = bf16(x[b][t][d]).
// ---------------------------------------------------------------------------
__global__ __launch_bounds__(256) void xpose_kernel(
    const float* __restrict__ x, u16* __restrict__ xT, u16* __restrict__ xbf) {
  __shared__ u16 tile[64][72];
  const int blk = blockIdx.x;
  const int b = blk >> 8;                 // 256 tiles per batch
  const int rem = blk & 255;
  const int t0 = (rem >> 3) * 64, d0 = (rem & 7) * 64;
  const int tid = threadIdx.x;

#pragma unroll
  for (int it = 0; it < 4; ++it) {
    int r = (tid >> 4) + it * 16;
    int c = (tid & 15) * 4;
    float4 v = *(const float4*)&x[(size_t)(b * Tn + t0 + r) * Dn + d0 + c];
    u16 b0 = f2bf(v.x), b1 = f2bf(v.y), b2 = f2bf(v.z), b3 = f2bf(v.w);
    tile[c + 0][r] = b0;
    tile[c + 1][r] = b1;
    tile[c + 2][r] = b2;
    tile[c + 3][r] = b3;
    u16x4 pv; pv[0] = b0; pv[1] = b1; pv[2] = b2; pv[3] = b3;
    *(u16x4*)&xbf[(size_t)(b * Tn + t0 + r) * Dn + d0 + c] = pv;
  }
  __syncthreads();
  const int dr = tid >> 2, ts = (tid & 3) * 16;
  u16x8 v0 = *(const u16x8*)&tile[dr][ts];
  u16x8 v1 = *(const u16x8*)&tile[dr][ts + 8];
  u16* dst = xT + (size_t)(b * Dn + d0 + dr) * Tn + t0 + ts;
  *(u16x8*)dst = v0;
  *(u16x8*)(dst + 8) = v1;
}

// ---------------------------------------------------------------------------
// Kernel 2: weight prep.  WqkT[n][d] = bf16(Wq|Wk[d][n]) (n<128 -> Wq),
//           WoT[n][d] = bf16(Wo[d][n]).
// ---------------------------------------------------------------------------
__global__ __launch_bounds__(256) void wprep_kernel(
    const float* __restrict__ Wq, const float* __restrict__ Wk,
    const float* __restrict__ Wo,
    u16* __restrict__ WqkT, u16* __restrict__ WoT) {
  __shared__ u16 tile[64][72];
  const int tid = threadIdx.x;
  const int blk = blockIdx.x;
  const float* src; u16* dst;
  int srcC, r0, c0, rowOff;
  if (blk < 32) {
    src = (blk < 16) ? Wq : Wk;
    rowOff = (blk < 16) ? 0 : 128;
    int t = blk & 15;
    r0 = (t >> 1) * 64; c0 = (t & 1) * 64;
    srcC = 128; dst = WqkT;
  } else {
    int t = blk - 32;
    src = Wo; rowOff = 0;
    r0 = (t >> 3) * 64; c0 = (t & 7) * 64;
    srcC = 512; dst = WoT;
  }
#pragma unroll
  for (int it = 0; it < 4; ++it) {
    int r = (tid >> 4) + it * 16;
    int c = (tid & 15) * 4;
    float4 v = *(const float4*)&src[(size_t)(r0 + r) * srcC + c0 + c];
    tile[c + 0][r] = f2bf(v.x);
    tile[c + 1][r] = f2bf(v.y);
    tile[c + 2][r] = f2bf(v.z);
    tile[c + 3][r] = f2bf(v.w);
  }
  __syncthreads();
  const int dr = tid >> 2, ts = (tid & 3) * 16;
  u16x8 v0 = *(const u16x8*)&tile[dr][ts];
  u16x8 v1 = *(const u16x8*)&tile[dr][ts + 8];
  u16* dp = dst + (size_t)(rowOff + c0 + dr) * 512 + r0 + ts;
  *(u16x8*)dp = v0;
  *(u16x8*)(dp + 8) = v1;
}

// ---------------------------------------------------------------------------
// Kernel 3: q|k = xbf @ WqkT^T + bias, MFMA.  Block = 64 rows x 256 cols.
// ---------------------------------------------------------------------------
__global__ __launch_bounds__(512) void qk_mfma_kernel(
    const u16* __restrict__ xbf, const u16* __restrict__ WqkT,
    const float* __restrict__ bq, const float* __restrict__ bk,
    u16* __restrict__ qbf, u16* __restrict__ kbf) {
  __shared__ u16 as_[2][64 * 64];     // 2 x 8 KB
  __shared__ u16 bs_[2][256 * 64];    // 2 x 32 KB
  const int tid = threadIdx.x, w = tid >> 6, l = tid & 63;
  const int r0 = blockIdx.x * 64;
  const int wr = w >> 2, wc = w & 3;  // wave tile: 32 rows x 64 cols

  f32x4 acc[2][4];
#pragma unroll
  for (int mm = 0; mm < 2; ++mm)
#pragma unroll
    for (int n = 0; n < 4; ++n) acc[mm][n] = (f32x4){0.f, 0.f, 0.f, 0.f};

  auto stageA = [&](int c, int buf) {
    int row = 8 * w + (l >> 3);
    int ss = (l & 7) ^ (row & 7);
    gload16(xbf + ((size_t)(r0 + row) * Dn + c * 64 + ss * 8),
            (char*)&as_[buf][0] + w * 1024);
  };
  auto stageB = [&](int c, int buf) {
#pragma unroll
    for (int ii = 0; ii < 4; ++ii) {
      int i = 4 * w + ii;
      int n = i * 8 + (l >> 3);
      int ss = (l & 7) ^ (n & 7);
      gload16(WqkT + ((size_t)n * Dn + c * 64 + ss * 8),
              (char*)&bs_[buf][0] + i * 1024);
    }
  };
  stageA(0, 0); stageB(0, 0);
  __syncthreads();
  for (int c = 0; c < 8; ++c) {
    if (c + 1 < 8) { stageA(c + 1, (c + 1) & 1); stageB(c + 1, (c + 1) & 1); }
    const u16* ab = &as_[c & 1][0];
    const u16* bb = &bs_[c & 1][0];
#pragma unroll
    for (int kk = 0; kk < 2; ++kk) {
      int rA0 = wr * 32 + (l & 15);
      int sA = ((l >> 4) + 4 * kk) ^ (rA0 & 7);
      bf16x8 a0 = *(const bf16x8*)(ab + rA0 * 64 + sA * 8);
      bf16x8 a1 = *(const bf16x8*)(ab + (rA0 + 16) * 64 + sA * 8);
#pragma unroll
      for (int n = 0; n < 4; ++n) {
        int rB = wc * 64 + n * 16 + (l & 15);
        int sB = ((l >> 4) + 4 * kk) ^ (rB & 7);
        bf16x8 bv = *(const bf16x8*)(bb + rB * 64 + sB * 8);
        acc[0][n] = mfma16(a0, bv, acc[0][n]);
        acc[1][n] = mfma16(a1, bv, acc[1][n]);
      }
    }
    __syncthreads();
  }
#pragma unroll
  for (int n = 0; n < 4; ++n) {
    int col = wc * 64 + n * 16 + (l & 15);
    float bias = (col < 128) ? bq[col] : bk[col - 128];
    u16* outp = (col < 128) ? (qbf + col) : (kbf + col - 128);
#pragma unroll
    for (int mm = 0; mm < 2; ++mm)
#pragma unroll
      for (int i = 0; i < 4; ++i) {
        int row = r0 + wr * 32 + mm * 16 + 4 * (l >> 4) + i;
        outp[(size_t)row * DKn] = f2bf(acc[mm][n][i] + bias);
      }
  }
}

// ---------------------------------------------------------------------------
// Kernel 4: banded scores + 3-window softmax -> combined weights.
// Block = 16 query rows, 256 threads.  XCD swizzle: one batch per XCD.
// ---------------------------------------------------------------------------
__global__ __launch_bounds__(256) void weights_kernel(
    const u16* __restrict__ qbf, const u16* __restrict__ kbf,
    u16* __restrict__ Wg) {
  __shared__ u16 S[WQB * WST];          // 24.8 KB bf16 e-values
  __shared__ float spart[4][WQB][3];    // 768 B ring-sum partials
  const int tid = threadIdx.x, w = tid >> 6, l = tid & 63;
  // XCD swizzle: 1024 blocks = 8 XCD x 128; XCD x owns batch x entirely.
  const int blk = (blockIdx.x & 7) * 128 + (blockIdx.x >> 3);
  const int b = blk >> 7;
  const int tt = blk & 127;
  const int t0 = tt * WQB;
  const int jbase = t0 - 360;
  const float scale = 0.08838834764831845f;   // 1/sqrt(128)

  // q fragments in registers (same 16 rows for all 4 waves)
  bf16x8 a[4];
  {
    int row = t0 + (l & 15);
    const u16* qp = qbf + (size_t)(b * Tn + row) * DKn + (l >> 4) * 8;
#pragma unroll
    for (int kk = 0; kk < 4; ++kk) a[kk] = *(const bf16x8*)(qp + kk * 32);
  }

  float s0[4], s1[4], s2[4];
#pragma unroll
  for (int i = 0; i < 4; ++i) { s0[i] = 0.f; s1[i] = 0.f; s2[i] = 0.f; }
  const int rbase = 4 * (l >> 4);

  // MFMA loop: 12 chunks of 64 j (wave w owns j-quarter w), no barriers
  for (int c = 0; c < 12; ++c) {
    int jj = c * 64 + w * 16 + (l & 15);
    int j = jbase + jj;
    int jc = j < 0 ? 0 : (j > Tn - 1 ? Tn - 1 : j);
    const u16* kp = kbf + (size_t)(b * Tn + jc) * DKn + (l >> 4) * 8;
    f32x4 acc = {0.f, 0.f, 0.f, 0.f};
#pragma unroll
    for (int kk = 0; kk < 4; ++kk)
      acc = mfma16(a[kk], *(const bf16x8*)(kp + kk * 32), acc);
    bool valid = (j >= 0) && (j < Tn);
#pragma unroll
    for (int i = 0; i < 4; ++i) {
      int r = rbase + i;
      int dist = jj - r - 360; dist = dist < 0 ? -dist : dist;
      float e = __expf(acc[i] * scale);
      e = (valid && dist <= 360) ? e : 0.f;
      S[r * WST + jj] = f2bf(e);
      bool in0 = dist <= 12, in1 = dist <= 84;
      s0[i] += in0 ? e : 0.f;
      s1[i] += (in1 && !in0) ? e : 0.f;
      s2[i] += in1 ? 0.f : e;
    }
  }

  // reduce ring sums over the 16 col-lanes, store per-wave partials
#pragma unroll
  for (int o = 1; o < 16; o <<= 1)
#pragma unroll
    for (int i = 0; i < 4; ++i) {
      s0[i] += __shfl_xor(s0[i], o);
      s1[i] += __shfl_xor(s1[i], o);
      s2[i] += __shfl_xor(s2[i], o);
    }
  if ((l & 15) == 0) {
#pragma unroll
    for (int i = 0; i < 4; ++i) {
      spart[w][rbase + i][0] = s0[i];
      spart[w][rbase + i][1] = s1[i];
      spart[w][rbase + i][2] = s2[i];
    }
  }
  __syncthreads();

  // combine & write.  Wave w owns rows 4w..4w+3.
  const int off = (tt & 3) * 16;            // row/col offset within pv tile
  const int pvblk = b * 32 + (tt >> 2);
#pragma unroll
  for (int rr = 0; rr < 4; ++rr) {
    int r = 4 * w + rr;
    float L0 = spart[0][r][0] + spart[1][r][0] + spart[2][r][0] + spart[3][r][0];
    float L1 = L0 + spart[0][r][1] + spart[1][r][1] + spart[2][r][1] + spart[3][r][1];
    float L2 = L1 + spart[0][r][2] + spart[1][r][2] + spart[2][r][2] + spart[3][r][2];
    float F2 = (1.f / 3.f) / L2;
    float F1 = (1.f / 3.f) / L1 + F2;
    float F0 = (1.f / 3.f) / L0 + F1;
    const int center = r + 360;
    u16* wrow = Wg + ((size_t)pvblk * QB + off + r) * WJ;
#pragma unroll
    for (int t = 0; t < 6; ++t) {
      int jjw = 2 * l + 128 * t;
      if (jjw < 736) {
        unsigned pv2 = *(const unsigned*)&S[r * WST + jjw];
        float e0 = bf2f((u16)(pv2 & 0xffff));
        float e1 = bf2f((u16)(pv2 >> 16));
        int d0 = jjw - center; d0 = d0 < 0 ? -d0 : d0;
        int d1 = jjw + 1 - center; d1 = d1 < 0 ? -d1 : d1;
        float c0 = e0 * (d0 <= 12 ? F0 : (d0 <= 84 ? F1 : F2));
        float c1 = e1 * (d1 <= 12 ? F0 : (d1 <= 84 ? F1 : F2));
        unsigned o2 = (unsigned)f2bf(c0) | ((unsigned)f2bf(c1) << 16);
        *(unsigned*)&wrow[off + jjw] = o2;
      }
    }
    // pad: zero pv columns [0,off) and [off+736, 832)
    if (l < 48) {
      int jjp = (l < (off >> 1)) ? 2 * l : 736 + 2 * l;
      *(unsigned*)&wrow[jjp] = 0u;
    }
  }
}

// ---------------------------------------------------------------------------
// Kernel 5: PV GEMM, split-D.  Block = 64 t x 256 d (half of D), KC=64.
// OUT[64 x 256] = Wg[64 x 832] @ xwin[832 x 256].  80 KB LDS -> 2 blocks/CU.
// XCD swizzle: 512 blocks = 8 XCD x 64; XCD x owns batch x (xT 2 MB L2-fit).
// ---------------------------------------------------------------------------
__global__ __launch_bounds__(512) void pv_kernel(
    const u16* __restrict__ Wg, const u16* __restrict__ xT,
    u16* __restrict__ accbf) {
  __shared__ u16 xs[2][256 * 64];  // 2 x 32 KB
  __shared__ u16 ws[2][QB * 64];   // 2 x 8 KB
  const int tid = threadIdx.x;
  const int w = tid >> 6, l = tid & 63;
  const int work = (blockIdx.x & 7) * 64 + (blockIdx.x >> 3);
  const int b = work >> 6;
  const int rem = work & 63;
  const int tt = rem >> 1;
  const int dh = rem & 1;          // which 256-col half of D
  const int t064 = tt * QB;
  const int jbase = t064 - 360;
  const int pvblk = b * 32 + tt;
  const int wr = w >> 2, wc = w & 3;   // wave tile: 32 t x 64 d

  f32x4 acc[2][4];
#pragma unroll
  for (int mm = 0; mm < 2; ++mm)
#pragma unroll
    for (int n = 0; n < 4; ++n) acc[mm][n] = (f32x4){0.f,0.f,0.f,0.f};

  auto stage = [&](int c, int buf) {
#pragma unroll
    for (int ii = 0; ii < 4; ++ii) {
      int i = 4 * w + ii;
      int d = i * 8 + (l >> 3);          // 0..255 local d row
      int ss = (l & 7) ^ (d & 7);
      int g = jbase + c * 64 + ss * 8;
      g = g < 0 ? 0 : (g > Tn - 8 ? Tn - 8 : g);
      gload16(xT + ((size_t)(b * Dn + dh * 256 + d) * Tn + g),
              (char*)&xs[buf][0] + i * 1024);
    }
    int row = 8 * w + (l >> 3);
    int ss = (l & 7) ^ (row & 7);
    gload16(Wg + ((size_t)(pvblk * QB + row)) * WJ + c * 64 + ss * 8,
            (char*)&ws[buf][0] + w * 1024);
  };

  stage(0, 0);
  __syncthreads();
  for (int c = 0; c < NCH; ++c) {
    if (c + 1 < NCH) stage(c + 1, (c + 1) & 1);
    const u16* xb = &xs[c & 1][0];
    const u16* wb = &ws[c & 1][0];
#pragma unroll
    for (int kk = 0; kk < 2; ++kk) {
      int rA0 = wr * 32 + (l & 15);
      int sA = ((l >> 4) + 4 * kk) ^ (rA0 & 7);
      bf16x8 a0 = *(const bf16x8*)(wb + rA0 * 64 + sA * 8);
      bf16x8 a1 = *(const bf16x8*)(wb + (rA0 + 16) * 64 + sA * 8);
#pragma unroll
      for (int n = 0; n < 4; ++n) {
        int rB = wc * 64 + n * 16 + (l & 15);
        int sB = ((l >> 4) + 4 * kk) ^ (rB & 7);
        bf16x8 bv = *(const bf16x8*)(xb + rB * 64 + sB * 8);
        acc[0][n] = mfma16(a0, bv, acc[0][n]);
        acc[1][n] = mfma16(a1, bv, acc[1][n]);
      }
    }
    __syncthreads();
  }
#pragma unroll
  for (int mm = 0; mm < 2; ++mm)
#pragma unroll
    for (int n = 0; n < 4; ++n)
#pragma unroll
      for (int i = 0; i < 4; ++i) {
        int row = wr * 32 + mm * 16 + 4 * (l >> 4) + i;
        int col = dh * 256 + wc * 64 + n * 16 + (l & 15);
        accbf[(size_t)(b * Tn + t064 + row) * Dn + col] = f2bf(acc[mm][n][i]);
      }
}

// ---------------------------------------------------------------------------
// Kernel 6: OUT = LN(accbf @ WoT^T + bo + x) * gamma + beta, MFMA fused.
// ---------------------------------------------------------------------------
__global__ __launch_bounds__(512) void out_ln_mfma_kernel(
    const u16* __restrict__ accbf, const float* __restrict__ x,
    const u16* __restrict__ WoT, const float* __restrict__ bo,
    const float* __restrict__ gamma, const float* __restrict__ beta,
    float* __restrict__ out) {
  __shared__ u16 as_[2][64 * 64];     // 2 x 8 KB
  __shared__ u16 bs_[2][512 * 64];    // 2 x 64 KB
  __shared__ float red[64][4][2];     // 2 KB
  const int tid = threadIdx.x, w = tid >> 6, l = tid & 63;
  const int r0 = blockIdx.x * 64;
  const int wr = w >> 2, wc = w & 3;

  f32x4 acc[2][8];
#pragma unroll
  for (int mm = 0; mm < 2; ++mm)
#pragma unroll
    for (int n = 0; n < 8; ++n) acc[mm][n] = (f32x4){0.f,0.f,0.f,0.f};

  auto stageA = [&](int c, int buf) {
    int row = 8 * w + (l >> 3);
    int ss = (l & 7) ^ (row & 7);
    gload16(accbf + ((size_t)(r0 + row) * Dn + c * 64 + ss * 8),
            (char*)&as_[buf][0] + w * 1024);
  };
  auto stageB = [&](int c, int buf) {
#pragma unroll
    for (int ii = 0; ii < 8; ++ii) {
      int i = 8 * w + ii;
      int n = i * 8 + (l >> 3);
      int ss = (l & 7) ^ (n & 7);
      gload16(WoT + ((size_t)n * Dn + c * 64 + ss * 8),
              (char*)&bs_[buf][0] + i * 1024);
    }
  };
  stageA(0, 0); stageB(0, 0);
  __syncthreads();
  for (int c = 0; c < 8; ++c) {
    if (c + 1 < 8) { stageA(c + 1, (c + 1) & 1); stageB(c + 1, (c + 1) & 1); }
    const u16* ab = &as_[c & 1][0];
    const u16* bb = &bs_[c & 1][0];
#pragma unroll
    for (int kk = 0; kk < 2; ++kk) {
      int rA0 = wr * 32 + (l & 15);
      int sA = ((l >> 4) + 4 * kk) ^ (rA0 & 7);
      bf16x8 a0 = *(const bf16x8*)(ab + rA0 * 64 + sA * 8);
      bf16x8 a1 = *(const bf16x8*)(ab + (rA0 + 16) * 64 + sA * 8);
#pragma unroll
      for (int n = 0; n < 8; ++n) {
        int rB = wc * 128 + n * 16 + (l & 15);
        int sB = ((l >> 4) + 4 * kk) ^ (rB & 7);
        bf16x8 bv = *(const bf16x8*)(bb + rB * 64 + sB * 8);
        acc[0][n] = mfma16(a0, bv, acc[0][n]);
        acc[1][n] = mfma16(a1, bv, acc[1][n]);
      }
    }
    __syncthreads();
  }

  // epilogue: bias + residual, then LayerNorm
  float g_[8], be_[8], bo_[8];
#pragma unroll
  for (int n = 0; n < 8; ++n) {
    int col = wc * 128 + n * 16 + (l & 15);
    bo_[n] = bo[col]; g_[n] = gamma[col]; be_[n] = beta[col];
  }
#pragma unroll
  for (int mm = 0; mm < 2; ++mm)
#pragma unroll
    for (int i = 0; i < 4; ++i) {
      int row = r0 + wr * 32 + mm * 16 + 4 * (l >> 4) + i;
#pragma unroll
      for (int n = 0; n < 8; ++n) {
        int col = wc * 128 + n * 16 + (l & 15);
        acc[mm][n][i] += bo_[n] + x[(size_t)row * Dn + col];
      }
    }
#pragma unroll
  for (int mm = 0; mm < 2; ++mm)
#pragma unroll
    for (int i = 0; i < 4; ++i) {
      float s = 0.f, s2 = 0.f;
#pragma unroll
      for (int n = 0; n < 8; ++n) { float v = acc[mm][n][i]; s += v; s2 += v * v; }
#pragma unroll
      for (int o = 8; o; o >>= 1) { s += __shfl_xor(s, o); s2 += __shfl_xor(s2, o); }
      if ((l & 15) == 0) {
        int rl = wr * 32 + mm * 16 + 4 * (l >> 4) + i;
        red[rl][wc][0] = s; red[rl][wc][1] = s2;
      }
    }
  __syncthreads();
#pragma unroll
  for (int mm = 0; mm < 2; ++mm)
#pragma unroll
    for (int i = 0; i < 4; ++i) {
      int rl = wr * 32 + mm * 16 + 4 * (l >> 4) + i;
      float s  = red[rl][0][0] + red[rl][1][0] + red[rl][2][0] + red[rl][3][0];
      float s2 = red[rl][0][1] + red[rl][1][1] + red[rl][2][1] + red[rl][3][1];
      float mean = s * (1.f / 512.f);
      float var  = s2 * (1.f / 512.f) - mean * mean;
      float inv  = rsqrtf(var + 1e-5f);
      int row = r0 + rl;
#pragma unroll
      for (int n = 0; n < 8; ++n) {
        int col = wc * 128 + n * 16 + (l & 15);
        out[(size_t)row * Dn + col] = (acc[mm][n][i] - mean) * inv * g_[n] + be_[n];
      }
    }
}

// ---------------------------------------------------------------------------
extern "C" void kernel_launch(void* const* d_in, const int* in_sizes, int n_in,
                              void* d_out, int out_size, void* d_ws, size_t ws_size,
                              hipStream_t stream) {
  const float* x     = (const float*)d_in[0];
  const float* Wq    = (const float*)d_in[1];
  const float* bq    = (const float*)d_in[2];
  const float* Wk    = (const float*)d_in[3];
  const float* bk    = (const float*)d_in[4];
  const float* Wo    = (const float*)d_in[5];
  const float* bo    = (const float*)d_in[6];
  const float* gamma = (const float*)d_in[7];
  const float* beta  = (const float*)d_in[8];
  float* out = (float*)d_out;

  // workspace (u16 elems)
  u16* qbf   = (u16*)d_ws;
  u16* kbf   = qbf   + (size_t)Bn * Tn * DKn;          // +2,097,152
  u16* xT    = kbf   + (size_t)Bn * Tn * DKn;          // +2,097,152
  u16* xbf   = xT    + (size_t)Bn * Dn * Tn;           // +8,388,608
  u16* Wg    = xbf   + (size_t)Bn * Tn * Dn;           // +8,388,608
  u16* accbf = Wg    + (size_t)Bn * 32 * QB * WJ;      // +13,631,488
  u16* WqkT  = accbf + (size_t)Bn * Tn * Dn;           // +8,388,608
  u16* WoT   = WqkT  + (size_t)256 * 512;              // +131,072

  xpose_kernel<<<Bn * 256, 256, 0, stream>>>(x, xT, xbf);
  wprep_kernel<<<96, 256, 0, stream>>>(Wq, Wk, Wo, WqkT, WoT);
  qk_mfma_kernel<<<Bn * Tn / 64, 512, 0, stream>>>(xbf, WqkT, bq, bk, qbf, kbf);
  weights_kernel<<<Bn * 128, 256, 0, stream>>>(qbf, kbf, Wg);
  pv_kernel<<<Bn * 64, 512, 0, stream>>>(Wg, xT, accbf);
  out_ln_mfma_kernel<<<Bn * Tn / 64, 512, 0, stream>>>(accbf, x, WoT, bo, gamma, beta, out);
}